// Round 1
// baseline (8243.267 us; speedup 1.0000x reference)
//
#include <hip/hip_runtime.h>
#include <hip/hip_bf16.h>

// Problem dims
#define N_IN  80
#define N_OUT 25
#define FD    4096
#define HD    512
#define ED    512
#define VD    4096
#define BD    128
#define BOS   4093
#define TSEQ  105

// ---------------------------------------------------------------------------
// Generic fp32 GEMM: C[m][n] = act( sum_k A[m*lda+k] * W[n*ldw+k] + bias[n] )
// Tiles 64x64, BK=32, 256 threads, 4x4 per thread. M,N multiples of 64; K mult of 32.
// ---------------------------------------------------------------------------
template<int ACT>
__global__ __launch_bounds__(256)
void gemm_bias(const float* __restrict__ A, int lda,
               const float* __restrict__ W, int ldw,
               const float* __restrict__ bias,
               float* __restrict__ C, int ldc, int K)
{
    __shared__ float As[32][68];
    __shared__ float Ws[32][68];
    const int tid = threadIdx.x;
    const int tx = tid & 15, ty = tid >> 4;
    const int m0 = blockIdx.y * 64, n0 = blockIdx.x * 64;
    float acc[4][4] = {};
    for (int k0 = 0; k0 < K; k0 += 32) {
#pragma unroll
        for (int r = 0; r < 2; ++r) {
            int f = tid + r * 256;
            int row = f >> 3, q = f & 7;
            float4 v = *reinterpret_cast<const float4*>(&A[(size_t)(m0 + row) * lda + k0 + q * 4]);
            As[q * 4 + 0][row] = v.x; As[q * 4 + 1][row] = v.y;
            As[q * 4 + 2][row] = v.z; As[q * 4 + 3][row] = v.w;
            float4 w = *reinterpret_cast<const float4*>(&W[(size_t)(n0 + row) * ldw + k0 + q * 4]);
            Ws[q * 4 + 0][row] = w.x; Ws[q * 4 + 1][row] = w.y;
            Ws[q * 4 + 2][row] = w.z; Ws[q * 4 + 3][row] = w.w;
        }
        __syncthreads();
#pragma unroll
        for (int kk = 0; kk < 32; ++kk) {
            float4 a = *reinterpret_cast<const float4*>(&As[kk][ty * 4]);
            float4 w = *reinterpret_cast<const float4*>(&Ws[kk][tx * 4]);
            float av[4] = {a.x, a.y, a.z, a.w};
            float wv[4] = {w.x, w.y, w.z, w.w};
#pragma unroll
            for (int i = 0; i < 4; ++i)
#pragma unroll
                for (int jj = 0; jj < 4; ++jj) acc[i][jj] += av[i] * wv[jj];
        }
        __syncthreads();
    }
#pragma unroll
    for (int i = 0; i < 4; ++i) {
        int m = m0 + ty * 4 + i;
#pragma unroll
        for (int jj = 0; jj < 4; ++jj) {
            int n = n0 + tx * 4 + jj;
            float v = acc[i][jj] + bias[n];
            if (ACT == 1) v = v > 0.f ? v : 0.01f * v;
            C[(size_t)m * ldc + n] = v;
        }
    }
}

// ---------------------------------------------------------------------------
// Fused GRU recurrence step: gh = h@whh.T (+bhh), gates, h2.
// gi (with bih already added) precomputed. Grid (B/16, H/16), 256 threads.
// ---------------------------------------------------------------------------
__global__ __launch_bounds__(256)
void gru_step(const float* __restrict__ gi, const float* __restrict__ hprev,
              const float* __restrict__ whh, const float* __restrict__ bhh,
              float* __restrict__ hout)
{
    __shared__ float Hs[16][68];
    __shared__ float Wg[3][16][68];
    const int tid = threadIdx.x;
    const int tx = tid & 15, ty = tid >> 4;
    const int b0 = blockIdx.x * 16, j0 = blockIdx.y * 16;
    float ar = 0.f, az = 0.f, an = 0.f;
    for (int k0 = 0; k0 < 512; k0 += 64) {
        *reinterpret_cast<float4*>(&Hs[ty][tx * 4]) =
            *reinterpret_cast<const float4*>(&hprev[(size_t)(b0 + ty) * 512 + k0 + tx * 4]);
#pragma unroll
        for (int g = 0; g < 3; ++g)
            *reinterpret_cast<float4*>(&Wg[g][ty][tx * 4]) =
                *reinterpret_cast<const float4*>(&whh[(size_t)(j0 + g * 512 + ty) * 512 + k0 + tx * 4]);
        __syncthreads();
#pragma unroll
        for (int kk = 0; kk < 64; kk += 4) {
            float4 h4 = *reinterpret_cast<const float4*>(&Hs[ty][kk]);
            float4 r4 = *reinterpret_cast<const float4*>(&Wg[0][tx][kk]);
            float4 z4 = *reinterpret_cast<const float4*>(&Wg[1][tx][kk]);
            float4 n4 = *reinterpret_cast<const float4*>(&Wg[2][tx][kk]);
            ar += h4.x * r4.x + h4.y * r4.y + h4.z * r4.z + h4.w * r4.w;
            az += h4.x * z4.x + h4.y * z4.y + h4.z * z4.z + h4.w * z4.w;
            an += h4.x * n4.x + h4.y * n4.y + h4.z * n4.z + h4.w * n4.w;
        }
        __syncthreads();
    }
    const int b = b0 + ty, jj = j0 + tx;
    float gr = gi[(size_t)b * 1536 + jj] + bhh[jj] + ar;
    float gz = gi[(size_t)b * 1536 + 512 + jj] + bhh[512 + jj] + az;
    float r = 1.f / (1.f + expf(-gr));
    float z = 1.f / (1.f + expf(-gz));
    float n = tanhf(gi[(size_t)b * 1536 + 1024 + jj] + r * (an + bhh[1024 + jj]));
    float hp = hprev[(size_t)b * 512 + jj];
    hout[(size_t)b * 512 + jj] = (1.f - z) * n + z * hp;
}

// ---------------------------------------------------------------------------
// Decoder GRU step with fused gi = x@wih.T (K=1536) + gh = h@whh.T (K=512)
// ---------------------------------------------------------------------------
__global__ __launch_bounds__(256)
void dec_gru_step(const float* __restrict__ x, const float* __restrict__ hprev,
                  const float* __restrict__ wih, const float* __restrict__ whh,
                  const float* __restrict__ bih, const float* __restrict__ bhh,
                  float* __restrict__ hout)
{
    __shared__ float Xs[16][68];
    __shared__ float Wg[3][16][68];
    const int tid = threadIdx.x;
    const int tx = tid & 15, ty = tid >> 4;
    const int b0 = blockIdx.x * 16, j0 = blockIdx.y * 16;
    float air = 0.f, aiz = 0.f, ain = 0.f;
    for (int k0 = 0; k0 < 1536; k0 += 64) {
        *reinterpret_cast<float4*>(&Xs[ty][tx * 4]) =
            *reinterpret_cast<const float4*>(&x[(size_t)(b0 + ty) * 1536 + k0 + tx * 4]);
#pragma unroll
        for (int g = 0; g < 3; ++g)
            *reinterpret_cast<float4*>(&Wg[g][ty][tx * 4]) =
                *reinterpret_cast<const float4*>(&wih[(size_t)(j0 + g * 512 + ty) * 1536 + k0 + tx * 4]);
        __syncthreads();
#pragma unroll
        for (int kk = 0; kk < 64; kk += 4) {
            float4 h4 = *reinterpret_cast<const float4*>(&Xs[ty][kk]);
            float4 r4 = *reinterpret_cast<const float4*>(&Wg[0][tx][kk]);
            float4 z4 = *reinterpret_cast<const float4*>(&Wg[1][tx][kk]);
            float4 n4 = *reinterpret_cast<const float4*>(&Wg[2][tx][kk]);
            air += h4.x * r4.x + h4.y * r4.y + h4.z * r4.z + h4.w * r4.w;
            aiz += h4.x * z4.x + h4.y * z4.y + h4.z * z4.z + h4.w * z4.w;
            ain += h4.x * n4.x + h4.y * n4.y + h4.z * n4.z + h4.w * n4.w;
        }
        __syncthreads();
    }
    float ahr = 0.f, ahz = 0.f, ahn = 0.f;
    for (int k0 = 0; k0 < 512; k0 += 64) {
        *reinterpret_cast<float4*>(&Xs[ty][tx * 4]) =
            *reinterpret_cast<const float4*>(&hprev[(size_t)(b0 + ty) * 512 + k0 + tx * 4]);
#pragma unroll
        for (int g = 0; g < 3; ++g)
            *reinterpret_cast<float4*>(&Wg[g][ty][tx * 4]) =
                *reinterpret_cast<const float4*>(&whh[(size_t)(j0 + g * 512 + ty) * 512 + k0 + tx * 4]);
        __syncthreads();
#pragma unroll
        for (int kk = 0; kk < 64; kk += 4) {
            float4 h4 = *reinterpret_cast<const float4*>(&Xs[ty][kk]);
            float4 r4 = *reinterpret_cast<const float4*>(&Wg[0][tx][kk]);
            float4 z4 = *reinterpret_cast<const float4*>(&Wg[1][tx][kk]);
            float4 n4 = *reinterpret_cast<const float4*>(&Wg[2][tx][kk]);
            ahr += h4.x * r4.x + h4.y * r4.y + h4.z * r4.z + h4.w * r4.w;
            ahz += h4.x * z4.x + h4.y * z4.y + h4.z * z4.z + h4.w * z4.w;
            ahn += h4.x * n4.x + h4.y * n4.y + h4.z * n4.z + h4.w * n4.w;
        }
        __syncthreads();
    }
    const int b = b0 + ty, jj = j0 + tx;
    float r = 1.f / (1.f + expf(-(air + bih[jj] + ahr + bhh[jj])));
    float z = 1.f / (1.f + expf(-(aiz + bih[512 + jj] + ahz + bhh[512 + jj])));
    float n = tanhf(ain + bih[1024 + jj] + r * (ahn + bhh[1024 + jj]));
    float hp = hprev[(size_t)b * 512 + jj];
    hout[(size_t)b * 512 + jj] = (1.f - z) * n + z * hp;
}

// ---------------------------------------------------------------------------
// Attention + x assembly. One block per batch element.
// s[i] = tanh(dot(encA[b,i,:], h[b,:])), w = softmax(s), c = sum_i w_i encA[b,i,:]
// x[b] = [ d[b], enc_out[80+j][b], c ]
// ---------------------------------------------------------------------------
__global__ __launch_bounds__(256)
void attn_x(const float* __restrict__ enc, const float* __restrict__ h,
            const float* __restrict__ dvec, float* __restrict__ x, int j)
{
    const int b = blockIdx.x, tid = threadIdx.x;
    __shared__ float hsh[512];
    __shared__ float ssh[80];
    __shared__ float sinv;
    hsh[tid] = h[(size_t)b * 512 + tid];
    hsh[256 + tid] = h[(size_t)b * 512 + 256 + tid];
    __syncthreads();
    const int wave = tid >> 6, lane = tid & 63;
    for (int i = wave; i < 80; i += 4) {
        const float* row = enc + (size_t)i * (BD * HD) + (size_t)b * 512;
        float p = 0.f;
#pragma unroll
        for (int q = 0; q < 8; ++q) p += row[lane + 64 * q] * hsh[lane + 64 * q];
#pragma unroll
        for (int off = 32; off > 0; off >>= 1) p += __shfl_xor(p, off, 64);
        if (lane == 0) ssh[i] = tanhf(p);
    }
    __syncthreads();
    if (tid == 0) {
        float mx = -1e30f;
        for (int i = 0; i < 80; ++i) mx = fmaxf(mx, ssh[i]);
        float s = 0.f;
        for (int i = 0; i < 80; ++i) { float e = expf(ssh[i] - mx); ssh[i] = e; s += e; }
        sinv = 1.0f / s;
    }
    __syncthreads();
    float inv = sinv;
    for (int hc = tid; hc < 512; hc += 256) {
        float acc = 0.f;
        for (int i = 0; i < 80; ++i) acc += ssh[i] * enc[(size_t)i * (BD * HD) + (size_t)b * 512 + hc];
        x[(size_t)b * 1536 + 1024 + hc] = acc * inv;
        x[(size_t)b * 1536 + hc] = dvec[(size_t)b * 512 + hc];
        x[(size_t)b * 1536 + 512 + hc] = enc[(size_t)(80 + j) * (BD * HD) + (size_t)b * 512 + hc];
    }
}

// ---------------------------------------------------------------------------
// log-softmax loss + argmax feedback. One block per batch element.
// ---------------------------------------------------------------------------
__global__ __launch_bounds__(256)
void loss_reduce(const float* __restrict__ logits, const int* __restrict__ tgt,
                 const float* __restrict__ embed, float* __restrict__ dvec,
                 float* __restrict__ dout, int j)
{
    const int b = blockIdx.x, tid = threadIdx.x;
    __shared__ float rmax[256];
    __shared__ int   rarg[256];
    __shared__ float rsum[256];
    const float* lg = logits + (size_t)b * 4096;
    float lmax = -1e30f; int larg = 0;
    for (int v = tid; v < 4096; v += 256) {
        float f = lg[v];
        if (f > lmax) { lmax = f; larg = v; }
    }
    rmax[tid] = lmax; rarg[tid] = larg;
    __syncthreads();
    for (int s = 128; s > 0; s >>= 1) {
        if (tid < s) {
            float o = rmax[tid + s]; int oi = rarg[tid + s];
            if (o > rmax[tid] || (o == rmax[tid] && oi < rarg[tid])) { rmax[tid] = o; rarg[tid] = oi; }
        }
        __syncthreads();
    }
    float gmax = rmax[0]; int garg = rarg[0];
    float s = 0.f;
    for (int v = tid; v < 4096; v += 256) s += expf(lg[v] - gmax);
    rsum[tid] = s;
    __syncthreads();
    for (int t = 128; t > 0; t >>= 1) { if (tid < t) rsum[tid] += rsum[tid + t]; __syncthreads(); }
    if (tid == 0) {
        float lse = gmax + logf(rsum[0]);
        int tj = tgt[b * 25 + j];
        float lb = -(lg[tj] - lse);
        atomicAdd(dout, lb * (1.0f / 3200.0f));
    }
    for (int t = tid; t < 512; t += 256) dvec[(size_t)b * 512 + t] = embed[(size_t)garg * 512 + t];
}

__global__ void init_dvec(const float* __restrict__ embed, float* __restrict__ dvec)
{
    int idx = blockIdx.x * 256 + threadIdx.x; // 65536 total
    dvec[idx] = embed[(size_t)BOS * 512 + (idx & 511)];
}

__global__ void gi_fill(const float* __restrict__ bih, float* __restrict__ gi)
{
    int idx = blockIdx.x * 256 + threadIdx.x; // 25*128*1536 total
    gi[(size_t)10240 * 1536 + idx] = bih[idx % 1536];
}

// ---------------------------------------------------------------------------
extern "C" void kernel_launch(void* const* d_in, const int* in_sizes, int n_in,
                              void* d_out, int out_size, void* d_ws, size_t ws_size,
                              hipStream_t stream)
{
    const float* feats   = (const float*)d_in[0];
    const float* fc_w    = (const float*)d_in[1];
    const float* fc_b    = (const float*)d_in[2];
    const float* enc_wih = (const float*)d_in[3];
    const float* enc_whh = (const float*)d_in[4];
    const float* enc_bih = (const float*)d_in[5];
    const float* enc_bhh = (const float*)d_in[6];
    const float* dec_wih = (const float*)d_in[7];
    const float* dec_whh = (const float*)d_in[8];
    const float* dec_bih = (const float*)d_in[9];
    const float* dec_bhh = (const float*)d_in[10];
    const float* out_w   = (const float*)d_in[11];
    const float* out_b   = (const float*)d_in[12];
    const float* embed   = (const float*)d_in[13];
    const int*   tgt     = (const int*)d_in[14];

    float* ws  = (float*)d_ws;
    float* out = (float*)d_out;

    // workspace layout (floats)
    float* enc_gi  = ws;                 // 105*128*1536 = 20,643,840 (reused as dec1_gi)
    float* enc_out = ws + 20643840;      // 105*128*512 = 6,881,280
    float* xp      = ws + 27525120;      // 80*128*512  = 5,242,880
    float* h0      = ws + 32768000;      // 65,536 (zeros)
    float* h_a     = ws + 32833536;      // 65,536
    float* h_b     = ws + 32899072;      // 65,536
    float* xbuf    = ws + 32964608;      // 128*1536 = 196,608
    float* logits  = ws + 33161216;      // 128*4096 = 524,288
    float* dvec    = ws + 33685504;      // 65,536

    hipMemsetAsync(h0, 0, 65536 * sizeof(float), stream);
    hipMemsetAsync(d_out, 0, sizeof(float), stream);
    init_dvec<<<256, 256, 0, stream>>>(embed, dvec);

    // fc: xp = leaky_relu(feats @ fc_w.T + fc_b)   M=10240 K=4096 N=512
    gemm_bias<1><<<dim3(8, 160), 256, 0, stream>>>(feats, 4096, fc_w, 4096, fc_b, xp, 512, 4096);
    // enc gi for t<80: enc_gi = xp @ enc_wih.T + enc_bih   M=10240 K=512 N=1536
    gemm_bias<0><<<dim3(24, 160), 256, 0, stream>>>(xp, 512, enc_wih, 512, enc_bih, enc_gi, 1536, 512);
    // enc gi for t>=80 (x=0): just the bias
    gi_fill<<<19200, 256, 0, stream>>>(enc_bih, enc_gi);

    // encoder recurrence: 105 steps, h_t written into enc_out[t]
    for (int t = 0; t < 105; ++t) {
        const float* hp = (t == 0) ? h0 : enc_out + (size_t)(t - 1) * 65536;
        gru_step<<<dim3(8, 32), 256, 0, stream>>>(enc_gi + (size_t)t * 196608, hp,
                                                  enc_whh, enc_bhh, enc_out + (size_t)t * 65536);
    }

    // dec1 gi: enc_out @ dec_wih[:,1024:].T + dec_bih   M=10240 K=512 N=1536
    gemm_bias<0><<<dim3(24, 160), 256, 0, stream>>>(enc_out, 512, dec_wih + 1024, 1536, dec_bih, enc_gi, 1536, 512);
    // dec1 recurrence: 80 steps, only final h (alpha) matters
    for (int t = 0; t < 80; ++t) {
        const float* hp = (t == 0) ? h0 : (((t - 1) & 1) ? h_b : h_a);
        float* ho = (t & 1) ? h_b : h_a;
        gru_step<<<dim3(8, 32), 256, 0, stream>>>(enc_gi + (size_t)t * 196608, hp, dec_whh, dec_bhh, ho);
    }

    // attention decoder: 25 steps
    float* h_cur = h_b;   // t=79 wrote h_b
    float* h_next = h_a;
    for (int j = 0; j < 25; ++j) {
        attn_x<<<128, 256, 0, stream>>>(enc_out, h_cur, dvec, xbuf, j);
        dec_gru_step<<<dim3(8, 32), 256, 0, stream>>>(xbuf, h_cur, dec_wih, dec_whh,
                                                      dec_bih, dec_bhh, h_next);
        gemm_bias<0><<<dim3(64, 2), 256, 0, stream>>>(h_next, 512, out_w, 512, out_b, logits, 4096, 512);
        loss_reduce<<<128, 256, 0, stream>>>(logits, tgt, embed, dvec, out, j);
        float* tmp = h_cur; h_cur = h_next; h_next = tmp;
    }
}

// Round 2
// 7317.955 us; speedup vs baseline: 1.1264x; 1.1264x over previous
//
#include <hip/hip_runtime.h>
#include <hip/hip_bf16.h>

// Problem dims
#define N_IN  80
#define N_OUT 25
#define FD    4096
#define HD    512
#define ED    512
#define VD    4096
#define BD    128
#define BOS   4093

typedef __attribute__((ext_vector_type(8))) short bf16x8;
typedef __attribute__((ext_vector_type(4))) float f32x4;

__device__ inline unsigned short f2bf(float f) {
    unsigned int u = __builtin_bit_cast(unsigned int, f);
    unsigned int r = (u + 0x7fffu + ((u >> 16) & 1u)) >> 16;
    return (unsigned short)r;
}

// ---------------------------------------------------------------------------
// bf16 MFMA GEMM: C[m][n] = act( sum_k A[m][k] * W[n][k] + bias[n] )
// A: fp32 (cast in staging) if AFP32 else bf16(u16). W: bf16(u16).
// C: bf16(u16) if OUT_BF else fp32. Tile 128x128, BK=32, 4 waves.
// M%128==0, N%128==0, K%32==0.
// ---------------------------------------------------------------------------
template<int AFP32, int OUT_BF, int ACT>
__global__ __launch_bounds__(256)
void gemm_mfma(const void* __restrict__ Ap, int lda,
               const unsigned short* __restrict__ W, int ldw,
               const float* __restrict__ bias,
               void* __restrict__ Cp, int ldc, int K)
{
    __shared__ short Abuf[128 * 32];
    __shared__ short Wbuf[128 * 32];
    const int tid  = threadIdx.x;
    const int lane = tid & 63;
    const int wave = tid >> 6;
    const int wr = wave >> 1, wc = wave & 1;
    const int l15 = lane & 15, kg = lane >> 4;
    const int m0 = blockIdx.y * 128, n0 = blockIdx.x * 128;

    const float* Af = (const float*)Ap;
    const unsigned short* Ab = (const unsigned short*)Ap;

    f32x4 acc[4][4];
#pragma unroll
    for (int i = 0; i < 4; ++i)
#pragma unroll
        for (int j = 0; j < 4; ++j) acc[i][j] = f32x4{0.f, 0.f, 0.f, 0.f};

    const bf16x8* Av = (const bf16x8*)Abuf;
    const bf16x8* Wv = (const bf16x8*)Wbuf;

    for (int k0 = 0; k0 < K; k0 += 32) {
        // stage A and W tiles: 512 chunks of 8 bf16 each, 2 per thread
#pragma unroll
        for (int cc = 0; cc < 2; ++cc) {
            int c = tid + cc * 256;
            int row = c >> 2, k8 = (c & 3) * 8;
            if (AFP32) {
                const float* src = &Af[(size_t)(m0 + row) * lda + k0 + k8];
                float4 v0 = *reinterpret_cast<const float4*>(src);
                float4 v1 = *reinterpret_cast<const float4*>(src + 4);
                bf16x8 s;
                s[0] = (short)f2bf(v0.x); s[1] = (short)f2bf(v0.y);
                s[2] = (short)f2bf(v0.z); s[3] = (short)f2bf(v0.w);
                s[4] = (short)f2bf(v1.x); s[5] = (short)f2bf(v1.y);
                s[6] = (short)f2bf(v1.z); s[7] = (short)f2bf(v1.w);
                *reinterpret_cast<bf16x8*>(&Abuf[row * 32 + k8]) = s;
            } else {
                *reinterpret_cast<bf16x8*>(&Abuf[row * 32 + k8]) =
                    *reinterpret_cast<const bf16x8*>(&Ab[(size_t)(m0 + row) * lda + k0 + k8]);
            }
            *reinterpret_cast<bf16x8*>(&Wbuf[row * 32 + k8]) =
                *reinterpret_cast<const bf16x8*>(&W[(size_t)(n0 + row) * ldw + k0 + k8]);
        }
        __syncthreads();
        bf16x8 a[4], b[4];
#pragma unroll
        for (int i = 0; i < 4; ++i) a[i] = Av[(wr * 64 + i * 16 + l15) * 4 + kg];
#pragma unroll
        for (int j = 0; j < 4; ++j) b[j] = Wv[(wc * 64 + j * 16 + l15) * 4 + kg];
#pragma unroll
        for (int i = 0; i < 4; ++i)
#pragma unroll
            for (int j = 0; j < 4; ++j)
                acc[i][j] = __builtin_amdgcn_mfma_f32_16x16x32_bf16(a[i], b[j], acc[i][j], 0, 0, 0);
        __syncthreads();
    }

    float* Cf = (float*)Cp;
    unsigned short* Cb = (unsigned short*)Cp;
#pragma unroll
    for (int i = 0; i < 4; ++i) {
#pragma unroll
        for (int j = 0; j < 4; ++j) {
            int n = n0 + wc * 64 + j * 16 + l15;
            float bv = bias[n];
#pragma unroll
            for (int r = 0; r < 4; ++r) {
                int m = m0 + wr * 64 + i * 16 + kg * 4 + r;
                float v = acc[i][j][r] + bv;
                if (ACT == 1) v = v > 0.f ? v : 0.01f * v;
                if (OUT_BF) Cb[(size_t)m * ldc + n] = f2bf(v);
                else        Cf[(size_t)m * ldc + n] = v;
            }
        }
    }
}

// ---------------------------------------------------------------------------
// fp32 GEMM (kept for logits): C = A @ W.T + bias. 64x64 tile.
// ---------------------------------------------------------------------------
template<int ACT>
__global__ __launch_bounds__(256)
void gemm_bias(const float* __restrict__ A, int lda,
               const float* __restrict__ W, int ldw,
               const float* __restrict__ bias,
               float* __restrict__ C, int ldc, int K)
{
    __shared__ float As[32][68];
    __shared__ float Ws[32][68];
    const int tid = threadIdx.x;
    const int tx = tid & 15, ty = tid >> 4;
    const int m0 = blockIdx.y * 64, n0 = blockIdx.x * 64;
    float acc[4][4] = {};
    for (int k0 = 0; k0 < K; k0 += 32) {
#pragma unroll
        for (int r = 0; r < 2; ++r) {
            int f = tid + r * 256;
            int row = f >> 3, q = f & 7;
            float4 v = *reinterpret_cast<const float4*>(&A[(size_t)(m0 + row) * lda + k0 + q * 4]);
            As[q * 4 + 0][row] = v.x; As[q * 4 + 1][row] = v.y;
            As[q * 4 + 2][row] = v.z; As[q * 4 + 3][row] = v.w;
            float4 w = *reinterpret_cast<const float4*>(&W[(size_t)(n0 + row) * ldw + k0 + q * 4]);
            Ws[q * 4 + 0][row] = w.x; Ws[q * 4 + 1][row] = w.y;
            Ws[q * 4 + 2][row] = w.z; Ws[q * 4 + 3][row] = w.w;
        }
        __syncthreads();
#pragma unroll
        for (int kk = 0; kk < 32; ++kk) {
            float4 a = *reinterpret_cast<const float4*>(&As[kk][ty * 4]);
            float4 w = *reinterpret_cast<const float4*>(&Ws[kk][tx * 4]);
            float av[4] = {a.x, a.y, a.z, a.w};
            float wv[4] = {w.x, w.y, w.z, w.w};
#pragma unroll
            for (int i = 0; i < 4; ++i)
#pragma unroll
                for (int jj = 0; jj < 4; ++jj) acc[i][jj] += av[i] * wv[jj];
        }
        __syncthreads();
    }
#pragma unroll
    for (int i = 0; i < 4; ++i) {
        int m = m0 + ty * 4 + i;
#pragma unroll
        for (int jj = 0; jj < 4; ++jj) {
            int n = n0 + tx * 4 + jj;
            float v = acc[i][jj] + bias[n];
            if (ACT == 1) v = v > 0.f ? v : 0.01f * v;
            C[(size_t)m * ldc + n] = v;
        }
    }
}

// ---------------------------------------------------------------------------
// Fused GRU recurrence step (fp32): gh = h@whh.T (+bhh), gates, h2.
// Also writes a bf16 copy of h2 (for downstream MFMA GEMM input).
// ---------------------------------------------------------------------------
__global__ __launch_bounds__(256)
void gru_step(const float* __restrict__ gi, const float* __restrict__ hprev,
              const float* __restrict__ whh, const float* __restrict__ bhh,
              float* __restrict__ hout, unsigned short* __restrict__ hout_bf)
{
    __shared__ float Hs[16][68];
    __shared__ float Wg[3][16][68];
    const int tid = threadIdx.x;
    const int tx = tid & 15, ty = tid >> 4;
    const int b0 = blockIdx.x * 16, j0 = blockIdx.y * 16;
    float ar = 0.f, az = 0.f, an = 0.f;
    for (int k0 = 0; k0 < 512; k0 += 64) {
        *reinterpret_cast<float4*>(&Hs[ty][tx * 4]) =
            *reinterpret_cast<const float4*>(&hprev[(size_t)(b0 + ty) * 512 + k0 + tx * 4]);
#pragma unroll
        for (int g = 0; g < 3; ++g)
            *reinterpret_cast<float4*>(&Wg[g][ty][tx * 4]) =
                *reinterpret_cast<const float4*>(&whh[(size_t)(j0 + g * 512 + ty) * 512 + k0 + tx * 4]);
        __syncthreads();
#pragma unroll
        for (int kk = 0; kk < 64; kk += 4) {
            float4 h4 = *reinterpret_cast<const float4*>(&Hs[ty][kk]);
            float4 r4 = *reinterpret_cast<const float4*>(&Wg[0][tx][kk]);
            float4 z4 = *reinterpret_cast<const float4*>(&Wg[1][tx][kk]);
            float4 n4 = *reinterpret_cast<const float4*>(&Wg[2][tx][kk]);
            ar += h4.x * r4.x + h4.y * r4.y + h4.z * r4.z + h4.w * r4.w;
            az += h4.x * z4.x + h4.y * z4.y + h4.z * z4.z + h4.w * z4.w;
            an += h4.x * n4.x + h4.y * n4.y + h4.z * n4.z + h4.w * n4.w;
        }
        __syncthreads();
    }
    const int b = b0 + ty, jj = j0 + tx;
    float gr = gi[(size_t)b * 1536 + jj] + bhh[jj] + ar;
    float gz = gi[(size_t)b * 1536 + 512 + jj] + bhh[512 + jj] + az;
    float r = 1.f / (1.f + expf(-gr));
    float z = 1.f / (1.f + expf(-gz));
    float n = tanhf(gi[(size_t)b * 1536 + 1024 + jj] + r * (an + bhh[1024 + jj]));
    float hp = hprev[(size_t)b * 512 + jj];
    float v = (1.f - z) * n + z * hp;
    hout[(size_t)b * 512 + jj] = v;
    hout_bf[(size_t)b * 512 + jj] = f2bf(v);
}

// ---------------------------------------------------------------------------
// Decoder GRU step with fused gi = x@wih.T (K=1536) + gh = h@whh.T (K=512)
// ---------------------------------------------------------------------------
__global__ __launch_bounds__(256)
void dec_gru_step(const float* __restrict__ x, const float* __restrict__ hprev,
                  const float* __restrict__ wih, const float* __restrict__ whh,
                  const float* __restrict__ bih, const float* __restrict__ bhh,
                  float* __restrict__ hout)
{
    __shared__ float Xs[16][68];
    __shared__ float Wg[3][16][68];
    const int tid = threadIdx.x;
    const int tx = tid & 15, ty = tid >> 4;
    const int b0 = blockIdx.x * 16, j0 = blockIdx.y * 16;
    float air = 0.f, aiz = 0.f, ain = 0.f;
    for (int k0 = 0; k0 < 1536; k0 += 64) {
        *reinterpret_cast<float4*>(&Xs[ty][tx * 4]) =
            *reinterpret_cast<const float4*>(&x[(size_t)(b0 + ty) * 1536 + k0 + tx * 4]);
#pragma unroll
        for (int g = 0; g < 3; ++g)
            *reinterpret_cast<float4*>(&Wg[g][ty][tx * 4]) =
                *reinterpret_cast<const float4*>(&wih[(size_t)(j0 + g * 512 + ty) * 1536 + k0 + tx * 4]);
        __syncthreads();
#pragma unroll
        for (int kk = 0; kk < 64; kk += 4) {
            float4 h4 = *reinterpret_cast<const float4*>(&Xs[ty][kk]);
            float4 r4 = *reinterpret_cast<const float4*>(&Wg[0][tx][kk]);
            float4 z4 = *reinterpret_cast<const float4*>(&Wg[1][tx][kk]);
            float4 n4 = *reinterpret_cast<const float4*>(&Wg[2][tx][kk]);
            air += h4.x * r4.x + h4.y * r4.y + h4.z * r4.z + h4.w * r4.w;
            aiz += h4.x * z4.x + h4.y * z4.y + h4.z * z4.z + h4.w * z4.w;
            ain += h4.x * n4.x + h4.y * n4.y + h4.z * n4.z + h4.w * n4.w;
        }
        __syncthreads();
    }
    float ahr = 0.f, ahz = 0.f, ahn = 0.f;
    for (int k0 = 0; k0 < 512; k0 += 64) {
        *reinterpret_cast<float4*>(&Xs[ty][tx * 4]) =
            *reinterpret_cast<const float4*>(&hprev[(size_t)(b0 + ty) * 512 + k0 + tx * 4]);
#pragma unroll
        for (int g = 0; g < 3; ++g)
            *reinterpret_cast<float4*>(&Wg[g][ty][tx * 4]) =
                *reinterpret_cast<const float4*>(&whh[(size_t)(j0 + g * 512 + ty) * 512 + k0 + tx * 4]);
        __syncthreads();
#pragma unroll
        for (int kk = 0; kk < 64; kk += 4) {
            float4 h4 = *reinterpret_cast<const float4*>(&Xs[ty][kk]);
            float4 r4 = *reinterpret_cast<const float4*>(&Wg[0][tx][kk]);
            float4 z4 = *reinterpret_cast<const float4*>(&Wg[1][tx][kk]);
            float4 n4 = *reinterpret_cast<const float4*>(&Wg[2][tx][kk]);
            ahr += h4.x * r4.x + h4.y * r4.y + h4.z * r4.z + h4.w * r4.w;
            ahz += h4.x * z4.x + h4.y * z4.y + h4.z * z4.z + h4.w * z4.w;
            ahn += h4.x * n4.x + h4.y * n4.y + h4.z * n4.z + h4.w * n4.w;
        }
        __syncthreads();
    }
    const int b = b0 + ty, jj = j0 + tx;
    float r = 1.f / (1.f + expf(-(air + bih[jj] + ahr + bhh[jj])));
    float z = 1.f / (1.f + expf(-(aiz + bih[512 + jj] + ahz + bhh[512 + jj])));
    float n = tanhf(ain + bih[1024 + jj] + r * (ahn + bhh[1024 + jj]));
    float hp = hprev[(size_t)b * 512 + jj];
    hout[(size_t)b * 512 + jj] = (1.f - z) * n + z * hp;
}

// ---------------------------------------------------------------------------
// Attention + x assembly. One block per batch element.
// ---------------------------------------------------------------------------
__global__ __launch_bounds__(256)
void attn_x(const float* __restrict__ enc, const float* __restrict__ h,
            const float* __restrict__ dvec, float* __restrict__ x, int j)
{
    const int b = blockIdx.x, tid = threadIdx.x;
    __shared__ float hsh[512];
    __shared__ float ssh[80];
    __shared__ float sinv;
    hsh[tid] = h[(size_t)b * 512 + tid];
    hsh[256 + tid] = h[(size_t)b * 512 + 256 + tid];
    __syncthreads();
    const int wave = tid >> 6, lane = tid & 63;
    for (int i = wave; i < 80; i += 4) {
        const float* row = enc + (size_t)i * (BD * HD) + (size_t)b * 512;
        float p = 0.f;
#pragma unroll
        for (int q = 0; q < 8; ++q) p += row[lane + 64 * q] * hsh[lane + 64 * q];
#pragma unroll
        for (int off = 32; off > 0; off >>= 1) p += __shfl_xor(p, off, 64);
        if (lane == 0) ssh[i] = tanhf(p);
    }
    __syncthreads();
    if (tid == 0) {
        float mx = -1e30f;
        for (int i = 0; i < 80; ++i) mx = fmaxf(mx, ssh[i]);
        float s = 0.f;
        for (int i = 0; i < 80; ++i) { float e = expf(ssh[i] - mx); ssh[i] = e; s += e; }
        sinv = 1.0f / s;
    }
    __syncthreads();
    float inv = sinv;
    for (int hc = tid; hc < 512; hc += 256) {
        float acc = 0.f;
        for (int i = 0; i < 80; ++i) acc += ssh[i] * enc[(size_t)i * (BD * HD) + (size_t)b * 512 + hc];
        x[(size_t)b * 1536 + 1024 + hc] = acc * inv;
        x[(size_t)b * 1536 + hc] = dvec[(size_t)b * 512 + hc];
        x[(size_t)b * 1536 + 512 + hc] = enc[(size_t)(80 + j) * (BD * HD) + (size_t)b * 512 + hc];
    }
}

// ---------------------------------------------------------------------------
// log-softmax loss + argmax feedback. One block per batch element.
// ---------------------------------------------------------------------------
__global__ __launch_bounds__(256)
void loss_reduce(const float* __restrict__ logits, const int* __restrict__ tgt,
                 const float* __restrict__ embed, float* __restrict__ dvec,
                 float* __restrict__ dout, int j)
{
    const int b = blockIdx.x, tid = threadIdx.x;
    __shared__ float rmax[256];
    __shared__ int   rarg[256];
    __shared__ float rsum[256];
    const float* lg = logits + (size_t)b * 4096;
    float lmax = -1e30f; int larg = 0;
    for (int v = tid; v < 4096; v += 256) {
        float f = lg[v];
        if (f > lmax) { lmax = f; larg = v; }
    }
    rmax[tid] = lmax; rarg[tid] = larg;
    __syncthreads();
    for (int s = 128; s > 0; s >>= 1) {
        if (tid < s) {
            float o = rmax[tid + s]; int oi = rarg[tid + s];
            if (o > rmax[tid] || (o == rmax[tid] && oi < rarg[tid])) { rmax[tid] = o; rarg[tid] = oi; }
        }
        __syncthreads();
    }
    float gmax = rmax[0]; int garg = rarg[0];
    float s = 0.f;
    for (int v = tid; v < 4096; v += 256) s += expf(lg[v] - gmax);
    rsum[tid] = s;
    __syncthreads();
    for (int t = 128; t > 0; t >>= 1) { if (tid < t) rsum[tid] += rsum[tid + t]; __syncthreads(); }
    if (tid == 0) {
        float lse = gmax + logf(rsum[0]);
        int tj = tgt[b * 25 + j];
        float lb = -(lg[tj] - lse);
        atomicAdd(dout, lb * (1.0f / 3200.0f));
    }
    for (int t = tid; t < 512; t += 256) dvec[(size_t)b * 512 + t] = embed[(size_t)garg * 512 + t];
}

__global__ void init_dvec(const float* __restrict__ embed, float* __restrict__ dvec)
{
    int idx = blockIdx.x * 256 + threadIdx.x; // 65536 total
    dvec[idx] = embed[(size_t)BOS * 512 + (idx & 511)];
}

__global__ void gi_fill(const float* __restrict__ bih, float* __restrict__ gi)
{
    int idx = blockIdx.x * 256 + threadIdx.x; // 25*128*1536 total
    gi[(size_t)10240 * 1536 + idx] = bih[idx % 1536];
}

// fp32 -> bf16 cast, 4 elems per thread (n % 1024 == 0 for all our uses)
__global__ void cast_f2b(const float* __restrict__ in, unsigned short* __restrict__ out, int n)
{
    int i = (blockIdx.x * 256 + threadIdx.x) * 4;
    if (i < n) {
        float4 v = *reinterpret_cast<const float4*>(&in[i]);
        out[i + 0] = f2bf(v.x); out[i + 1] = f2bf(v.y);
        out[i + 2] = f2bf(v.z); out[i + 3] = f2bf(v.w);
    }
}

// dec_wih[:, 1024:1536] -> bf16, row-major 1536x512
__global__ void cast_slice(const float* __restrict__ in, unsigned short* __restrict__ out)
{
    int idx = blockIdx.x * 256 + threadIdx.x; // 786432 total
    int r = idx >> 9, c = idx & 511;
    out[idx] = f2bf(in[(size_t)r * 1536 + 1024 + c]);
}

// ---------------------------------------------------------------------------
extern "C" void kernel_launch(void* const* d_in, const int* in_sizes, int n_in,
                              void* d_out, int out_size, void* d_ws, size_t ws_size,
                              hipStream_t stream)
{
    const float* feats   = (const float*)d_in[0];
    const float* fc_w    = (const float*)d_in[1];
    const float* fc_b    = (const float*)d_in[2];
    const float* enc_wih = (const float*)d_in[3];
    const float* enc_whh = (const float*)d_in[4];
    const float* enc_bih = (const float*)d_in[5];
    const float* enc_bhh = (const float*)d_in[6];
    const float* dec_wih = (const float*)d_in[7];
    const float* dec_whh = (const float*)d_in[8];
    const float* dec_bih = (const float*)d_in[9];
    const float* dec_bhh = (const float*)d_in[10];
    const float* out_w   = (const float*)d_in[11];
    const float* out_b   = (const float*)d_in[12];
    const float* embed   = (const float*)d_in[13];
    const int*   tgt     = (const int*)d_in[14];

    float* ws  = (float*)d_ws;
    float* out = (float*)d_out;

    // workspace layout (float units)
    float* enc_gi  = ws;                              // 20,643,840
    float* enc_out = ws + 20643840;                   // 6,881,280
    unsigned short* xp_bf     = (unsigned short*)(ws + 27525120); // 5,242,880 bf16
    unsigned short* encout_bf = (unsigned short*)(ws + 30146560); // 6,881,280 bf16
    unsigned short* fcw_bf    = (unsigned short*)(ws + 33587200); // 2,097,152 bf16
    unsigned short* encwih_bf = fcw_bf + 2097152;                 // 786,432 bf16
    unsigned short* decw_bf   = encwih_bf + 786432;               // 786,432 bf16
    float* h0      = ws + 35422208;                   // 65,536
    float* h_a     = ws + 35487744;
    float* h_b     = ws + 35553280;
    unsigned short* hbf_scr = (unsigned short*)(ws + 35618816);   // 65,536 bf16
    float* xbuf    = ws + 35651584;                   // 196,608
    float* logits  = ws + 35848192;                   // 524,288
    float* dvec    = ws + 36372480;                   // 65,536

    hipMemsetAsync(h0, 0, 65536 * sizeof(float), stream);
    hipMemsetAsync(d_out, 0, sizeof(float), stream);
    init_dvec<<<256, 256, 0, stream>>>(embed, dvec);

    // weight casts
    cast_f2b<<<2048, 256, 0, stream>>>(fc_w, fcw_bf, 2097152);
    cast_f2b<<<768, 256, 0, stream>>>(enc_wih, encwih_bf, 786432);
    cast_slice<<<3072, 256, 0, stream>>>(dec_wih, decw_bf);

    // fc: xp_bf = leaky_relu(feats @ fc_w.T + fc_b)   M=10240 K=4096 N=512
    gemm_mfma<1, 1, 1><<<dim3(4, 80), 256, 0, stream>>>(feats, 4096, fcw_bf, 4096, fc_b, xp_bf, 512, 4096);
    // enc gi (t<80): enc_gi = xp @ enc_wih.T + enc_bih   M=10240 K=512 N=1536
    gemm_mfma<0, 0, 0><<<dim3(12, 80), 256, 0, stream>>>(xp_bf, 512, encwih_bf, 512, enc_bih, enc_gi, 1536, 512);
    // enc gi (t>=80, x=0): bias only
    gi_fill<<<19200, 256, 0, stream>>>(enc_bih, enc_gi);

    // encoder recurrence: 105 steps
    for (int t = 0; t < 105; ++t) {
        const float* hp = (t == 0) ? h0 : enc_out + (size_t)(t - 1) * 65536;
        gru_step<<<dim3(8, 32), 256, 0, stream>>>(enc_gi + (size_t)t * 196608, hp,
                                                  enc_whh, enc_bhh,
                                                  enc_out + (size_t)t * 65536,
                                                  encout_bf + (size_t)t * 65536);
    }

    // dec1 gi: enc_out_bf @ dec_wih[:,1024:].T + dec_bih   M=10240 K=512 N=1536
    gemm_mfma<0, 0, 0><<<dim3(12, 80), 256, 0, stream>>>(encout_bf, 512, decw_bf, 512, dec_bih, enc_gi, 1536, 512);
    // dec1 recurrence: 80 steps, only final h (alpha) matters
    for (int t = 0; t < 80; ++t) {
        const float* hp = (t == 0) ? h0 : (((t - 1) & 1) ? h_b : h_a);
        float* ho = (t & 1) ? h_b : h_a;
        gru_step<<<dim3(8, 32), 256, 0, stream>>>(enc_gi + (size_t)t * 196608, hp, dec_whh, dec_bhh, ho, hbf_scr);
    }

    // attention decoder: 25 steps
    float* h_cur = h_b;   // t=79 wrote h_b
    float* h_next = h_a;
    for (int j = 0; j < 25; ++j) {
        attn_x<<<128, 256, 0, stream>>>(enc_out, h_cur, dvec, xbuf, j);
        dec_gru_step<<<dim3(8, 32), 256, 0, stream>>>(xbuf, h_cur, dec_wih, dec_whh,
                                                      dec_bih, dec_bhh, h_next);
        gemm_bias<0><<<dim3(64, 2), 256, 0, stream>>>(h_next, 512, out_w, 512, out_b, logits, 4096, 512);
        loss_reduce<<<128, 256, 0, stream>>>(logits, tgt, embed, dvec, out, j);
        float* tmp = h_cur; h_cur = h_next; h_next = tmp;
    }
}